// Round 2
// baseline (4239.013 us; speedup 1.0000x reference)
//
#include <hip/hip_runtime.h>
#include <cstddef>

typedef _Float16 half8   __attribute__((ext_vector_type(8)));
typedef _Float16 half4_t __attribute__((ext_vector_type(4)));
typedef float    float4_t __attribute__((ext_vector_type(4)));

#define T_STEPS 128
#define BATCH   2048
#define DATA    64
#define DIM     128
#define WIDTH   256
#define SUBSTEPS 4
#define BT      16            // batch tile per workgroup (= MFMA N)
#define NWG     (BATCH / BT)  // 128 workgroups
#define NTHREADS 256          // 4 waves: fewer waves => less redundant LDS B-traffic
#define SPY (DIM + 8)         // 136 halfs -> 272 B row stride (16B multiple)
#define SPH (WIDTH + 8)       // 264 halfs -> 528 B row stride (16B multiple)

#define MFMA16(A, B, C) __builtin_amdgcn_mfma_f32_16x16x32_f16((A), (B), (C), 0, 0, 0)

__global__ __launch_bounds__(NTHREADS, 1)
void anode_kernel(const float* __restrict__ ts, const float* __restrict__ y0,
                  const float* __restrict__ W1, const float* __restrict__ b1,
                  const float* __restrict__ W2, const float* __restrict__ b2,
                  const float* __restrict__ W3, const float* __restrict__ b3,
                  float* __restrict__ out)
{
  // Activation ping-pong buffers, [n][k] layout, padded strides.
  __shared__ __align__(16) _Float16 Yb[BT * SPY];
  __shared__ __align__(16) _Float16 H1[BT * SPH];
  __shared__ __align__(16) _Float16 H2[BT * SPH];

  const int tid  = threadIdx.x;
  const int wave = tid >> 6;    // 0..3
  const int lane = tid & 63;
  const int n    = lane & 15;   // batch column (MFMA N index)
  const int quad = lane >> 4;   // 0..3
  const int bbase = blockIdx.x * BT;

  auto ld8 = [](const float* p) -> half8 {
    float4_t u0 = *(const float4_t*)p;
    float4_t u1 = *(const float4_t*)(p + 4);
    half8 r;
    r[0]=(_Float16)u0[0]; r[1]=(_Float16)u0[1]; r[2]=(_Float16)u0[2]; r[3]=(_Float16)u0[3];
    r[4]=(_Float16)u1[0]; r[5]=(_Float16)u1[1]; r[6]=(_Float16)u1[2]; r[7]=(_Float16)u1[3];
    return r;
  };

  // ---- Weights resident in VGPRs as MFMA A-fragments ----
  // A-layout (16x16x32): lane holds A[m = Mbase + (lane&15)][k = kt*32 + quad*8 + j]
  // L1/L2: wave w owns M rows [64w, 64w+64) as 4 M-tiles.
  // L3:    wave w owns M rows [32w, 32w+32) as 2 M-tiles.
  half8 a1[4][4];   // W1: 256x128
  half8 a2[4][8];   // W2: 256x256
  half8 a3[2][8];   // W3: 128x256
  float4_t bv1[4], bv2[4], bv3[2];

  #pragma unroll
  for (int mt = 0; mt < 4; ++mt) {
    const int m = wave * 64 + mt * 16 + n;
    #pragma unroll
    for (int kt = 0; kt < 4; ++kt)
      a1[mt][kt] = ld8(W1 + (size_t)m * DIM + kt * 32 + quad * 8);
    #pragma unroll
    for (int kt = 0; kt < 8; ++kt)
      a2[mt][kt] = ld8(W2 + (size_t)m * WIDTH + kt * 32 + quad * 8);
    bv1[mt] = *(const float4_t*)(b1 + wave * 64 + mt * 16 + quad * 4);
    bv2[mt] = *(const float4_t*)(b2 + wave * 64 + mt * 16 + quad * 4);
  }
  #pragma unroll
  for (int j = 0; j < 2; ++j) {
    const int m3 = wave * 32 + j * 16 + n;
    #pragma unroll
    for (int kt = 0; kt < 8; ++kt)
      a3[j][kt] = ld8(W3 + (size_t)m3 * WIDTH + kt * 32 + quad * 8);
    bv3[j] = *(const float4_t*)(b3 + wave * 32 + j * 16 + quad * 4);
  }

  // Per-lane LDS pointers.
  const _Float16* rdY  = Yb + n * SPY + quad * 8;
  const _Float16* rdH1 = H1 + n * SPH + quad * 8;
  const _Float16* rdH2 = H2 + n * SPH + quad * 8;
  _Float16* wrY0 = Yb + n * SPY + wave * 32 + quad * 4;        // state j=0
  _Float16* wrY1 = Yb + n * SPY + wave * 32 + 16 + quad * 4;   // state j=1
  _Float16* wrH  = H1 + n * SPH + wave * 64 + quad * 4;        // + mt*16
  _Float16* wrG  = H2 + n * SPH + wave * 64 + quad * 4;

  auto st4h = [](_Float16* p, float4_t v) {
    half4_t h;
    h[0]=(_Float16)v[0]; h[1]=(_Float16)v[1]; h[2]=(_Float16)v[2]; h[3]=(_Float16)v[3];
    *(half4_t*)p = h;
  };
  auto relu4 = [](float4_t v) -> float4_t {
    v[0]=fmaxf(v[0],0.f); v[1]=fmaxf(v[1],0.f); v[2]=fmaxf(v[2],0.f); v[3]=fmaxf(v[3],0.f);
    return v;
  };

  // State layout matches L3 output: lane owns dims d = 32*wave + 16*j + quad*4 + r.
  struct st2 { float4_t v0, v1; };

  auto feval = [&](st2 yin) -> st2 {
    st4h(wrY0, yin.v0);
    st4h(wrY1, yin.v1);
    __syncthreads();

    // layer 1: 256x128 @ 128x16 ; B fragment reused across 4 M-tiles
    float4_t c0 = bv1[0], c1 = bv1[1], c2 = bv1[2], c3 = bv1[3];
    #pragma unroll
    for (int kt = 0; kt < 4; ++kt) {
      half8 bk = *(const half8*)(rdY + kt * 32);
      c0 = MFMA16(a1[0][kt], bk, c0);
      c1 = MFMA16(a1[1][kt], bk, c1);
      c2 = MFMA16(a1[2][kt], bk, c2);
      c3 = MFMA16(a1[3][kt], bk, c3);
    }
    st4h(wrH,      relu4(c0));
    st4h(wrH + 16, relu4(c1));
    st4h(wrH + 32, relu4(c2));
    st4h(wrH + 48, relu4(c3));
    __syncthreads();

    // layer 2: 256x256 @ 256x16
    float4_t d0 = bv2[0], d1 = bv2[1], d2 = bv2[2], d3 = bv2[3];
    #pragma unroll
    for (int kt = 0; kt < 8; ++kt) {
      half8 bk = *(const half8*)(rdH1 + kt * 32);
      d0 = MFMA16(a2[0][kt], bk, d0);
      d1 = MFMA16(a2[1][kt], bk, d1);
      d2 = MFMA16(a2[2][kt], bk, d2);
      d3 = MFMA16(a2[3][kt], bk, d3);
    }
    st4h(wrG,      relu4(d0));
    st4h(wrG + 16, relu4(d1));
    st4h(wrG + 32, relu4(d2));
    st4h(wrG + 48, relu4(d3));
    __syncthreads();

    // layer 3: 128x256 @ 256x16 (linear)
    float4_t e0 = bv3[0], e1 = bv3[1];
    #pragma unroll
    for (int kt = 0; kt < 8; ++kt) {
      half8 bk = *(const half8*)(rdH2 + kt * 32);
      e0 = MFMA16(a3[0][kt], bk, e0);
      e1 = MFMA16(a3[1][kt], bk, e1);
    }
    return { e0, e1 };
  };

  // ---- state init ----
  st2 y;
  y.v0 = *(const float4_t*)(y0 + (size_t)(bbase + n) * DIM + wave * 32 + quad * 4);
  y.v1 = *(const float4_t*)(y0 + (size_t)(bbase + n) * DIM + wave * 32 + 16 + quad * 4);

  // ys[0] = y0 (first 64 dims -> waves 0,1)
  if (wave < 2) {
    *(float4_t*)(out + (size_t)(bbase + n) * DATA + wave * 32 + quad * 4) = y.v0;
    *(float4_t*)(out + (size_t)(bbase + n) * DATA + wave * 32 + 16 + quad * 4) = y.v1;
  }
  if (blockIdx.x == 0 && tid == 0)
    out[(size_t)T_STEPS * BATCH * DATA] = (float)((T_STEPS - 1) * SUBSTEPS); // 508.0f

  const float A31=(float)(3.0/40.0),      A32=(float)(9.0/40.0);
  const float A41=(float)(44.0/45.0),     A42=(float)(-56.0/15.0),    A43=(float)(32.0/9.0);
  const float A51=(float)(19372.0/6561.0),A52=(float)(-25360.0/2187.0),
              A53=(float)(64448.0/6561.0),A54=(float)(-212.0/729.0);
  const float A61=(float)(9017.0/3168.0), A62=(float)(-355.0/33.0),
              A63=(float)(46732.0/5247.0),A64=(float)(49.0/176.0),    A65=(float)(-5103.0/18656.0);
  const float B1=(float)(35.0/384.0),     B3=(float)(500.0/1113.0),   B4=(float)(125.0/192.0),
              B5=(float)(-2187.0/6784.0), B6=(float)(11.0/84.0);

  for (int t = 0; t < T_STEPS - 1; ++t) {
    const float dt = (ts[t + 1] - ts[t]) * (1.0f / SUBSTEPS);
    for (int s = 0; s < SUBSTEPS; ++s) {
      st2 k1 = feval(y);
      st2 k2 = feval({ y.v0 + (dt * 0.2f) * k1.v0,
                       y.v1 + (dt * 0.2f) * k1.v1 });
      st2 k3 = feval({ y.v0 + dt * (A31 * k1.v0 + A32 * k2.v0),
                       y.v1 + dt * (A31 * k1.v1 + A32 * k2.v1) });
      st2 k4 = feval({ y.v0 + dt * (A41 * k1.v0 + A42 * k2.v0 + A43 * k3.v0),
                       y.v1 + dt * (A41 * k1.v1 + A42 * k2.v1 + A43 * k3.v1) });
      st2 k5 = feval({ y.v0 + dt * (A51 * k1.v0 + A52 * k2.v0 + A53 * k3.v0 + A54 * k4.v0),
                       y.v1 + dt * (A51 * k1.v1 + A52 * k2.v1 + A53 * k3.v1 + A54 * k4.v1) });
      st2 k6 = feval({ y.v0 + dt * (A61 * k1.v0 + A62 * k2.v0 + A63 * k3.v0 + A64 * k4.v0 + A65 * k5.v0),
                       y.v1 + dt * (A61 * k1.v1 + A62 * k2.v1 + A63 * k3.v1 + A64 * k4.v1 + A65 * k5.v1) });
      y.v0 = y.v0 + dt * (B1 * k1.v0 + B3 * k3.v0 + B4 * k4.v0 + B5 * k5.v0 + B6 * k6.v0);
      y.v1 = y.v1 + dt * (B1 * k1.v1 + B3 * k3.v1 + B4 * k4.v1 + B5 * k5.v1 + B6 * k6.v1);
    }
    if (wave < 2) {
      float* o = out + (size_t)(t + 1) * (BATCH * DATA) + (size_t)(bbase + n) * DATA;
      *(float4_t*)(o + wave * 32 + quad * 4) = y.v0;
      *(float4_t*)(o + wave * 32 + 16 + quad * 4) = y.v1;
    }
  }
}

extern "C" void kernel_launch(void* const* d_in, const int* in_sizes, int n_in,
                              void* d_out, int out_size, void* d_ws, size_t ws_size,
                              hipStream_t stream) {
  (void)in_sizes; (void)n_in; (void)out_size; (void)d_ws; (void)ws_size;
  const float* ts = (const float*)d_in[0];
  const float* y0 = (const float*)d_in[1];
  const float* W1 = (const float*)d_in[2];
  const float* b1 = (const float*)d_in[3];
  const float* W2 = (const float*)d_in[4];
  const float* b2 = (const float*)d_in[5];
  const float* W3 = (const float*)d_in[6];
  const float* b3 = (const float*)d_in[7];
  anode_kernel<<<dim3(NWG), dim3(NTHREADS), 0, stream>>>(
      ts, y0, W1, b1, W2, b2, W3, b3, (float*)d_out);
}

// Round 3
// 3793.136 us; speedup vs baseline: 1.1175x; 1.1175x over previous
//
#include <hip/hip_runtime.h>
#include <cstddef>
#include <cstdint>

typedef _Float16 half8   __attribute__((ext_vector_type(8)));
typedef _Float16 half4_t __attribute__((ext_vector_type(4)));
typedef float    float4_t __attribute__((ext_vector_type(4)));
typedef long long ll2_t   __attribute__((ext_vector_type(2)));

#define T_STEPS 128
#define BATCH   2048
#define DATA    64
#define DIM     128
#define WIDTH   256
#define SUBSTEPS 4
#define BT      16            // batch tile per WG (= MFMA N)
#define NWG     (BATCH / BT)  // 128 WGs -> 128 CUs
#define NTHREADS 512          // 8 waves, 2/SIMD: latency hiding (R2 lesson)
#define SPY 136               // Yb row stride in halfs (272 B)
#define SPH8 272              // H row stride in BYTES (256 fp8 + 16 pad)

#define MFMA16(A, B, C) __builtin_amdgcn_mfma_f32_16x16x32_f16((A), (B), (C), 0, 0, 0)
#define MFMA8(A, B, C)  __builtin_amdgcn_mfma_f32_16x16x32_fp8_fp8((A), (B), (C), 0, 0, 0)

__global__ __launch_bounds__(NTHREADS, 2)
void anode_kernel(const float* __restrict__ ts, const float* __restrict__ y0,
                  const float* __restrict__ W1, const float* __restrict__ b1,
                  const float* __restrict__ W2, const float* __restrict__ b2,
                  const float* __restrict__ W3, const float* __restrict__ b3,
                  float* __restrict__ out)
{
  // Yb: fp16 [n][k] rows. H1/H2: fp8, fragment-major per n:
  //   byte(n,k) = n*SPH8 + ((k>>3)&3)*64 + (k>>5)*8 + (k&7)
  // so one lane's two consecutive K=32 fragments are 16 contiguous bytes.
  __shared__ __align__(16) _Float16 Yb[BT * SPY];
  __shared__ __align__(16) char H1[BT * SPH8];
  __shared__ __align__(16) char H2[BT * SPH8];

  const int tid  = threadIdx.x;
  const int wave = tid >> 6;    // 0..7
  const int lane = tid & 63;
  const int n    = lane & 15;   // batch column (MFMA N index)
  const int quad = lane >> 4;   // 0..3
  const int bbase = blockIdx.x * BT;

  auto ld8h = [](const float* p) -> half8 {
    float4_t u0 = *(const float4_t*)p;
    float4_t u1 = *(const float4_t*)(p + 4);
    half8 r;
    r[0]=(_Float16)u0[0]; r[1]=(_Float16)u0[1]; r[2]=(_Float16)u0[2]; r[3]=(_Float16)u0[3];
    r[4]=(_Float16)u1[0]; r[5]=(_Float16)u1[1]; r[6]=(_Float16)u1[2]; r[7]=(_Float16)u1[3];
    return r;
  };

  // --- fp8 pack/unpack (OCP e4m3 on gfx950) ---
  auto qpack = [](const float* w, float s) -> unsigned long long {
    unsigned int lo = 0, hi = 0;
    lo = __builtin_amdgcn_cvt_pk_fp8_f32(w[0]*s, w[1]*s, lo, false);
    lo = __builtin_amdgcn_cvt_pk_fp8_f32(w[2]*s, w[3]*s, lo, true);
    hi = __builtin_amdgcn_cvt_pk_fp8_f32(w[4]*s, w[5]*s, hi, false);
    hi = __builtin_amdgcn_cvt_pk_fp8_f32(w[6]*s, w[7]*s, hi, true);
    return (unsigned long long)lo | ((unsigned long long)hi << 32);
  };
  auto qdec = [](unsigned long long q, float* d) {
    unsigned int lo = (unsigned int)q, hi = (unsigned int)(q >> 32);
    d[0]=__builtin_amdgcn_cvt_f32_fp8(lo,0); d[1]=__builtin_amdgcn_cvt_f32_fp8(lo,1);
    d[2]=__builtin_amdgcn_cvt_f32_fp8(lo,2); d[3]=__builtin_amdgcn_cvt_f32_fp8(lo,3);
    d[4]=__builtin_amdgcn_cvt_f32_fp8(hi,0); d[5]=__builtin_amdgcn_cvt_f32_fp8(hi,1);
    d[6]=__builtin_amdgcn_cvt_f32_fp8(hi,2); d[7]=__builtin_amdgcn_cvt_f32_fp8(hi,3);
  };

  // ---- Weights in registers ----
  // L1 fp16 fragments (state input precision). L2/L3 double-fp8:
  //   W ~= hi + lo/256 ; lo = fp8(256*(W - dec(hi)))
  half8 a1[2][4];                       // W1 256x128, mt=2
  long long a2h[2][8], a2l[2][8];       // W2 256x256, mt=2
  long long a3h[8],    a3l[8];          // W3 128x256, mt3=1 (16 rows/wave)
  float4_t bv1[2], bv2[2], bv3;

  #pragma unroll
  for (int mt = 0; mt < 2; ++mt) {
    const int m = wave * 32 + mt * 16 + n;
    #pragma unroll
    for (int kt = 0; kt < 4; ++kt)
      a1[mt][kt] = ld8h(W1 + (size_t)m * DIM + kt * 32 + quad * 8);
    #pragma unroll
    for (int kt = 0; kt < 8; ++kt) {
      float w[8], d[8], r[8];
      #pragma unroll
      for (int j = 0; j < 8; ++j) w[j] = W2[(size_t)m * WIDTH + kt * 32 + quad * 8 + j];
      unsigned long long qh = qpack(w, 1.0f);
      qdec(qh, d);
      #pragma unroll
      for (int j = 0; j < 8; ++j) r[j] = w[j] - d[j];
      a2h[mt][kt] = (long long)qh;
      a2l[mt][kt] = (long long)qpack(r, 256.0f);
    }
    bv1[mt] = *(const float4_t*)(b1 + wave * 32 + mt * 16 + quad * 4);
    bv2[mt] = *(const float4_t*)(b2 + wave * 32 + mt * 16 + quad * 4);
  }
  {
    const int m3 = wave * 16 + n;
    #pragma unroll
    for (int kt = 0; kt < 8; ++kt) {
      float w[8], d[8], r[8];
      #pragma unroll
      for (int j = 0; j < 8; ++j) w[j] = W3[(size_t)m3 * WIDTH + kt * 32 + quad * 8 + j];
      unsigned long long qh = qpack(w, 1.0f);
      qdec(qh, d);
      #pragma unroll
      for (int j = 0; j < 8; ++j) r[j] = w[j] - d[j];
      a3h[kt] = (long long)qh;
      a3l[kt] = (long long)qpack(r, 256.0f);
    }
    bv3 = *(const float4_t*)(b3 + wave * 16 + quad * 4);
  }

  // Per-lane LDS pointers.
  const _Float16* rdY  = Yb + n * SPY + quad * 8;              // + kt*32 halfs
  const char* rdH1 = H1 + n * SPH8 + quad * 64;                // + kt2*16 bytes
  const char* rdH2 = H2 + n * SPH8 + quad * 64;
  _Float16* wrY = Yb + n * SPY + wave * 16 + quad * 4;
  // fp8 activation write addr for dim m (m multiple of 4):
  auto hwp = [&](char* base, int m) -> char* {
    return base + n * SPH8 + ((m >> 3) & 3) * 64 + (m >> 5) * 8 + (m & 7);
  };
  char* wrH1a = hwp(H1, wave * 32 + quad * 4);
  char* wrH1b = hwp(H1, wave * 32 + 16 + quad * 4);
  char* wrH2a = hwp(H2, wave * 32 + quad * 4);
  char* wrH2b = hwp(H2, wave * 32 + 16 + quad * 4);

  auto st4h = [](_Float16* p, float4_t v) {
    half4_t h;
    h[0]=(_Float16)v[0]; h[1]=(_Float16)v[1]; h[2]=(_Float16)v[2]; h[3]=(_Float16)v[3];
    *(half4_t*)p = h;
  };
  auto relu4 = [](float4_t v) -> float4_t {
    v[0]=fmaxf(v[0],0.f); v[1]=fmaxf(v[1],0.f); v[2]=fmaxf(v[2],0.f); v[3]=fmaxf(v[3],0.f);
    return v;
  };
  auto pack4 = [](float4_t v) -> unsigned int {
    unsigned int p = 0;
    p = __builtin_amdgcn_cvt_pk_fp8_f32(v[0], v[1], p, false);
    p = __builtin_amdgcn_cvt_pk_fp8_f32(v[2], v[3], p, true);
    return p;
  };

  // f(y): lane's state dims d = wave*16 + quad*4 + r (matches L3 C-layout).
  auto feval = [&](float4_t yin) -> float4_t {
    st4h(wrY, yin);
    __syncthreads();

    // L1 (fp16): 256x128 @ 128x16
    float4_t c0 = bv1[0], c1 = bv1[1];
    #pragma unroll
    for (int kt = 0; kt < 4; ++kt) {
      half8 bk = *(const half8*)(rdY + kt * 32);
      c0 = MFMA16(a1[0][kt], bk, c0);
      c1 = MFMA16(a1[1][kt], bk, c1);
    }
    *(unsigned int*)wrH1a = pack4(relu4(c0));
    *(unsigned int*)wrH1b = pack4(relu4(c1));
    __syncthreads();

    // L2 (double-fp8): 256x256 @ 256x16
    float4_t dh0 = bv2[0], dh1 = bv2[1];
    float4_t dl0 = {0.f,0.f,0.f,0.f}, dl1 = {0.f,0.f,0.f,0.f};
    #pragma unroll
    for (int kt2 = 0; kt2 < 4; ++kt2) {
      ll2_t bb = *(const ll2_t*)(rdH1 + kt2 * 16);   // fragments kt=2*kt2, 2*kt2+1
      dh0 = MFMA8(a2h[0][2*kt2],   bb[0], dh0);
      dh1 = MFMA8(a2h[1][2*kt2],   bb[0], dh1);
      dl0 = MFMA8(a2l[0][2*kt2],   bb[0], dl0);
      dl1 = MFMA8(a2l[1][2*kt2],   bb[0], dl1);
      dh0 = MFMA8(a2h[0][2*kt2+1], bb[1], dh0);
      dh1 = MFMA8(a2h[1][2*kt2+1], bb[1], dh1);
      dl0 = MFMA8(a2l[0][2*kt2+1], bb[1], dl0);
      dl1 = MFMA8(a2l[1][2*kt2+1], bb[1], dl1);
    }
    const float is = 1.0f / 256.0f;
    float4_t d0 = dh0 + is * dl0, d1 = dh1 + is * dl1;
    *(unsigned int*)wrH2a = pack4(relu4(d0));
    *(unsigned int*)wrH2b = pack4(relu4(d1));
    __syncthreads();

    // L3 (double-fp8): 128x256 @ 256x16, linear
    float4_t eh = bv3, el = {0.f,0.f,0.f,0.f};
    #pragma unroll
    for (int kt2 = 0; kt2 < 4; ++kt2) {
      ll2_t bb = *(const ll2_t*)(rdH2 + kt2 * 16);
      eh = MFMA8(a3h[2*kt2],   bb[0], eh);
      el = MFMA8(a3l[2*kt2],   bb[0], el);
      eh = MFMA8(a3h[2*kt2+1], bb[1], eh);
      el = MFMA8(a3l[2*kt2+1], bb[1], el);
    }
    return eh + is * el;
  };

  // ---- state init ----
  float4_t y = *(const float4_t*)(y0 + (size_t)(bbase + n) * DIM + wave * 16 + quad * 4);

  if (wave < 4)
    *(float4_t*)(out + (size_t)(bbase + n) * DATA + wave * 16 + quad * 4) = y;
  if (blockIdx.x == 0 && tid == 0)
    out[(size_t)T_STEPS * BATCH * DATA] = (float)((T_STEPS - 1) * SUBSTEPS); // 508.0f

  const float A31=(float)(3.0/40.0),      A32=(float)(9.0/40.0);
  const float A41=(float)(44.0/45.0),     A42=(float)(-56.0/15.0),    A43=(float)(32.0/9.0);
  const float A51=(float)(19372.0/6561.0),A52=(float)(-25360.0/2187.0),
              A53=(float)(64448.0/6561.0),A54=(float)(-212.0/729.0);
  const float A61=(float)(9017.0/3168.0), A62=(float)(-355.0/33.0),
              A63=(float)(46732.0/5247.0),A64=(float)(49.0/176.0),    A65=(float)(-5103.0/18656.0);
  const float B1=(float)(35.0/384.0),     B3=(float)(500.0/1113.0),   B4=(float)(125.0/192.0),
              B5=(float)(-2187.0/6784.0), B6=(float)(11.0/84.0);

  for (int t = 0; t < T_STEPS - 1; ++t) {
    const float dt = (ts[t + 1] - ts[t]) * (1.0f / SUBSTEPS);
    for (int s = 0; s < SUBSTEPS; ++s) {
      float4_t k1 = feval(y);
      float4_t k2 = feval(y + (dt * 0.2f) * k1);
      float4_t k3 = feval(y + dt * (A31 * k1 + A32 * k2));
      float4_t k4 = feval(y + dt * (A41 * k1 + A42 * k2 + A43 * k3));
      float4_t k5 = feval(y + dt * (A51 * k1 + A52 * k2 + A53 * k3 + A54 * k4));
      float4_t k6 = feval(y + dt * (A61 * k1 + A62 * k2 + A63 * k3 + A64 * k4 + A65 * k5));
      y = y + dt * (B1 * k1 + B3 * k3 + B4 * k4 + B5 * k5 + B6 * k6);
    }
    if (wave < 4)
      *(float4_t*)(out + (size_t)(t + 1) * (BATCH * DATA)
                       + (size_t)(bbase + n) * DATA + wave * 16 + quad * 4) = y;
  }
}

extern "C" void kernel_launch(void* const* d_in, const int* in_sizes, int n_in,
                              void* d_out, int out_size, void* d_ws, size_t ws_size,
                              hipStream_t stream) {
  (void)in_sizes; (void)n_in; (void)out_size; (void)d_ws; (void)ws_size;
  const float* ts = (const float*)d_in[0];
  const float* y0 = (const float*)d_in[1];
  const float* W1 = (const float*)d_in[2];
  const float* b1 = (const float*)d_in[3];
  const float* W2 = (const float*)d_in[4];
  const float* b2 = (const float*)d_in[5];
  const float* W3 = (const float*)d_in[6];
  const float* b3 = (const float*)d_in[7];
  anode_kernel<<<dim3(NWG), dim3(NTHREADS), 0, stream>>>(
      ts, y0, W1, b1, W2, b2, W3, b3, (float*)d_out);
}

// Round 4
// 2851.856 us; speedup vs baseline: 1.4864x; 1.3301x over previous
//
#include <hip/hip_runtime.h>
#include <cstddef>
#include <cstdint>

typedef _Float16 half8   __attribute__((ext_vector_type(8)));
typedef _Float16 half4_t __attribute__((ext_vector_type(4)));
typedef float    float4_t __attribute__((ext_vector_type(4)));
typedef long long ll2_t   __attribute__((ext_vector_type(2)));

#define T_STEPS 128
#define BATCH   2048
#define DATA    64
#define DIM     128
#define WIDTH   256
#define SUBSTEPS 4
#define BT      16            // batch tile per WG (= MFMA N)
#define NWG     (BATCH / BT)  // 128 WGs -> 128 CUs
#define NTHREADS 512          // 8 waves, 2/SIMD (R2 lesson: 1 wave/SIMD = latency death)
#define SPY 136               // Yb row stride in halfs (272 B)
#define SPH8 272              // H row stride in BYTES (256 fp8 + 16 pad)
#define WSCALE 16.0f          // pre-scale for fp8 weight pack (rms 1/16 -> ~1)
#define IWS (1.0f / 16.0f)

#define MFMA16(A, B, C) __builtin_amdgcn_mfma_f32_16x16x32_f16((A), (B), (C), 0, 0, 0)
#define MFMA8(A, B, C)  __builtin_amdgcn_mfma_f32_16x16x32_fp8_fp8((A), (B), (C), 0, 0, 0)

__global__ __launch_bounds__(NTHREADS, 2)
void anode_kernel(const float* __restrict__ ts, const float* __restrict__ y0,
                  const float* __restrict__ W1, const float* __restrict__ b1,
                  const float* __restrict__ W2, const float* __restrict__ b2,
                  const float* __restrict__ W3, const float* __restrict__ b3,
                  float* __restrict__ out)
{
  // Yb: fp16 [n][k] rows. H1/H2: fp8, fragment-major per n:
  //   byte(n,k) = n*SPH8 + ((k>>3)&3)*64 + (k>>5)*8 + (k&7)
  // one lane's two consecutive K=32 fragments = 16 contiguous bytes (1 b128).
  __shared__ __align__(16) _Float16 Yb[BT * SPY];
  __shared__ __align__(16) char H1[BT * SPH8];
  __shared__ __align__(16) char H2[BT * SPH8];

  const int tid  = threadIdx.x;
  const int wave = tid >> 6;    // 0..7
  const int lane = tid & 63;
  const int n    = lane & 15;   // batch column (MFMA N index)
  const int quad = lane >> 4;   // 0..3
  const int bbase = blockIdx.x * BT;

  auto ld8h = [](const float* p) -> half8 {
    float4_t u0 = *(const float4_t*)p;
    float4_t u1 = *(const float4_t*)(p + 4);
    half8 r;
    r[0]=(_Float16)u0[0]; r[1]=(_Float16)u0[1]; r[2]=(_Float16)u0[2]; r[3]=(_Float16)u0[3];
    r[4]=(_Float16)u1[0]; r[5]=(_Float16)u1[1]; r[6]=(_Float16)u1[2]; r[7]=(_Float16)u1[3];
    return r;
  };

  // fp8 (OCP e4m3) pack of 8 scaled weights.
  auto qpack = [](const float* w, float s) -> long long {
    unsigned int lo = 0, hi = 0;
    lo = __builtin_amdgcn_cvt_pk_fp8_f32(w[0]*s, w[1]*s, lo, false);
    lo = __builtin_amdgcn_cvt_pk_fp8_f32(w[2]*s, w[3]*s, lo, true);
    hi = __builtin_amdgcn_cvt_pk_fp8_f32(w[4]*s, w[5]*s, hi, false);
    hi = __builtin_amdgcn_cvt_pk_fp8_f32(w[6]*s, w[7]*s, hi, true);
    return (long long)((unsigned long long)lo | ((unsigned long long)hi << 32));
  };

  // ---- Weights in registers ----
  // A-layout: lane holds A[m = Mbase + n][k = kt*32 + quad*8 + j]
  half8 a1[2][4];        // W1 256x128 fp16, wave owns M rows [32w,32w+32)
  long long a2[2][8];    // W2 256x256 fp8 (x16 scaled)
  long long a3[8];       // W3 128x256 fp8 (x16 scaled), wave owns rows [16w,16w+16)
  float4_t bv1[2], bv2[2], bv3;

  #pragma unroll
  for (int mt = 0; mt < 2; ++mt) {
    const int m = wave * 32 + mt * 16 + n;
    #pragma unroll
    for (int kt = 0; kt < 4; ++kt)
      a1[mt][kt] = ld8h(W1 + (size_t)m * DIM + kt * 32 + quad * 8);
    #pragma unroll
    for (int kt = 0; kt < 8; ++kt) {
      float w[8];
      #pragma unroll
      for (int j = 0; j < 8; ++j) w[j] = W2[(size_t)m * WIDTH + kt * 32 + quad * 8 + j];
      a2[mt][kt] = qpack(w, WSCALE);
    }
    bv1[mt] = *(const float4_t*)(b1 + wave * 32 + mt * 16 + quad * 4);
    bv2[mt] = *(const float4_t*)(b2 + wave * 32 + mt * 16 + quad * 4);
  }
  {
    const int m3 = wave * 16 + n;
    #pragma unroll
    for (int kt = 0; kt < 8; ++kt) {
      float w[8];
      #pragma unroll
      for (int j = 0; j < 8; ++j) w[j] = W3[(size_t)m3 * WIDTH + kt * 32 + quad * 8 + j];
      a3[kt] = qpack(w, WSCALE);
    }
    bv3 = *(const float4_t*)(b3 + wave * 16 + quad * 4);
  }

  // Per-lane LDS pointers.
  const _Float16* rdY = Yb + n * SPY + quad * 8;   // + kt*32 halfs
  const char* rdH1 = H1 + n * SPH8 + quad * 64;    // + kt2*16 bytes
  const char* rdH2 = H2 + n * SPH8 + quad * 64;
  _Float16* wrY = Yb + n * SPY + wave * 16 + quad * 4;
  auto hwp = [&](char* base, int m) -> char* {
    return base + n * SPH8 + ((m >> 3) & 3) * 64 + (m >> 5) * 8 + (m & 7);
  };
  char* wrH1a = hwp(H1, wave * 32 + quad * 4);
  char* wrH1b = hwp(H1, wave * 32 + 16 + quad * 4);
  char* wrH2a = hwp(H2, wave * 32 + quad * 4);
  char* wrH2b = hwp(H2, wave * 32 + 16 + quad * 4);

  auto st4h = [](_Float16* p, float4_t v) {
    half4_t h;
    h[0]=(_Float16)v[0]; h[1]=(_Float16)v[1]; h[2]=(_Float16)v[2]; h[3]=(_Float16)v[3];
    *(half4_t*)p = h;
  };
  auto relu4 = [](float4_t v) -> float4_t {
    v[0]=fmaxf(v[0],0.f); v[1]=fmaxf(v[1],0.f); v[2]=fmaxf(v[2],0.f); v[3]=fmaxf(v[3],0.f);
    return v;
  };
  auto pack4 = [](float4_t v) -> unsigned int {
    unsigned int p = 0;
    p = __builtin_amdgcn_cvt_pk_fp8_f32(v[0], v[1], p, false);
    p = __builtin_amdgcn_cvt_pk_fp8_f32(v[2], v[3], p, true);
    return p;
  };

  // f(y): lane's state dims d = wave*16 + quad*4 + r (matches L3 C-layout).
  auto feval = [&](float4_t yin) -> float4_t {
    st4h(wrY, yin);
    __syncthreads();

    // L1 (fp16): 256x128 @ 128x16
    float4_t c0 = bv1[0], c1 = bv1[1];
    #pragma unroll
    for (int kt = 0; kt < 4; ++kt) {
      half8 bk = *(const half8*)(rdY + kt * 32);
      c0 = MFMA16(a1[0][kt], bk, c0);
      c1 = MFMA16(a1[1][kt], bk, c1);
    }
    *(unsigned int*)wrH1a = pack4(relu4(c0));
    *(unsigned int*)wrH1b = pack4(relu4(c1));
    __syncthreads();

    // L2 (fp8, x16-scaled weights): 256x256 @ 256x16; split chains (depth 4)
    float4_t d0a = {0,0,0,0}, d0b = {0,0,0,0}, d1a = {0,0,0,0}, d1b = {0,0,0,0};
    {
      ll2_t b0 = *(const ll2_t*)(rdH1);
      ll2_t b1v = *(const ll2_t*)(rdH1 + 16);
      ll2_t b2v = *(const ll2_t*)(rdH1 + 32);
      ll2_t b3v = *(const ll2_t*)(rdH1 + 48);
      d0a = MFMA8(a2[0][0], b0[0], d0a);  d1a = MFMA8(a2[1][0], b0[0], d1a);
      d0a = MFMA8(a2[0][1], b0[1], d0a);  d1a = MFMA8(a2[1][1], b0[1], d1a);
      d0a = MFMA8(a2[0][2], b1v[0], d0a); d1a = MFMA8(a2[1][2], b1v[0], d1a);
      d0a = MFMA8(a2[0][3], b1v[1], d0a); d1a = MFMA8(a2[1][3], b1v[1], d1a);
      d0b = MFMA8(a2[0][4], b2v[0], d0b); d1b = MFMA8(a2[1][4], b2v[0], d1b);
      d0b = MFMA8(a2[0][5], b2v[1], d0b); d1b = MFMA8(a2[1][5], b2v[1], d1b);
      d0b = MFMA8(a2[0][6], b3v[0], d0b); d1b = MFMA8(a2[1][6], b3v[0], d1b);
      d0b = MFMA8(a2[0][7], b3v[1], d0b); d1b = MFMA8(a2[1][7], b3v[1], d1b);
    }
    float4_t d0 = bv2[0] + IWS * (d0a + d0b);
    float4_t d1 = bv2[1] + IWS * (d1a + d1b);
    *(unsigned int*)wrH2a = pack4(relu4(d0));
    *(unsigned int*)wrH2b = pack4(relu4(d1));
    __syncthreads();

    // L3 (fp8, x16-scaled): 128x256 @ 256x16, linear; split chains
    float4_t ea = {0,0,0,0}, eb = {0,0,0,0};
    {
      ll2_t b0 = *(const ll2_t*)(rdH2);
      ll2_t b1v = *(const ll2_t*)(rdH2 + 16);
      ll2_t b2v = *(const ll2_t*)(rdH2 + 32);
      ll2_t b3v = *(const ll2_t*)(rdH2 + 48);
      ea = MFMA8(a3[0], b0[0], ea);
      ea = MFMA8(a3[1], b0[1], ea);
      ea = MFMA8(a3[2], b1v[0], ea);
      ea = MFMA8(a3[3], b1v[1], ea);
      eb = MFMA8(a3[4], b2v[0], eb);
      eb = MFMA8(a3[5], b2v[1], eb);
      eb = MFMA8(a3[6], b3v[0], eb);
      eb = MFMA8(a3[7], b3v[1], eb);
    }
    return bv3 + IWS * (ea + eb);
  };

  // ---- state init ----
  float4_t y = *(const float4_t*)(y0 + (size_t)(bbase + n) * DIM + wave * 16 + quad * 4);

  if (wave < 4)
    *(float4_t*)(out + (size_t)(bbase + n) * DATA + wave * 16 + quad * 4) = y;
  if (blockIdx.x == 0 && tid == 0)
    out[(size_t)T_STEPS * BATCH * DATA] = (float)((T_STEPS - 1) * SUBSTEPS); // 508.0f

  const float A31=(float)(3.0/40.0),      A32=(float)(9.0/40.0);
  const float A41=(float)(44.0/45.0),     A42=(float)(-56.0/15.0),    A43=(float)(32.0/9.0);
  const float A51=(float)(19372.0/6561.0),A52=(float)(-25360.0/2187.0),
              A53=(float)(64448.0/6561.0),A54=(float)(-212.0/729.0);
  const float A61=(float)(9017.0/3168.0), A62=(float)(-355.0/33.0),
              A63=(float)(46732.0/5247.0),A64=(float)(49.0/176.0),    A65=(float)(-5103.0/18656.0);
  const float B1=(float)(35.0/384.0),     B3=(float)(500.0/1113.0),   B4=(float)(125.0/192.0),
              B5=(float)(-2187.0/6784.0), B6=(float)(11.0/84.0);

  for (int t = 0; t < T_STEPS - 1; ++t) {
    const float dt = (ts[t + 1] - ts[t]) * (1.0f / SUBSTEPS);
    for (int s = 0; s < SUBSTEPS; ++s) {
      float4_t k1 = feval(y);
      float4_t k2 = feval(y + (dt * 0.2f) * k1);
      float4_t k3 = feval(y + dt * (A31 * k1 + A32 * k2));
      float4_t k4 = feval(y + dt * (A41 * k1 + A42 * k2 + A43 * k3));
      float4_t k5 = feval(y + dt * (A51 * k1 + A52 * k2 + A53 * k3 + A54 * k4));
      float4_t k6 = feval(y + dt * (A61 * k1 + A62 * k2 + A63 * k3 + A64 * k4 + A65 * k5));
      y = y + dt * (B1 * k1 + B3 * k3 + B4 * k4 + B5 * k5 + B6 * k6);
    }
    if (wave < 4)
      *(float4_t*)(out + (size_t)(t + 1) * (BATCH * DATA)
                       + (size_t)(bbase + n) * DATA + wave * 16 + quad * 4) = y;
  }
}

extern "C" void kernel_launch(void* const* d_in, const int* in_sizes, int n_in,
                              void* d_out, int out_size, void* d_ws, size_t ws_size,
                              hipStream_t stream) {
  (void)in_sizes; (void)n_in; (void)out_size; (void)d_ws; (void)ws_size;
  const float* ts = (const float*)d_in[0];
  const float* y0 = (const float*)d_in[1];
  const float* W1 = (const float*)d_in[2];
  const float* b1 = (const float*)d_in[3];
  const float* W2 = (const float*)d_in[4];
  const float* b2 = (const float*)d_in[5];
  const float* W3 = (const float*)d_in[6];
  const float* b3 = (const float*)d_in[7];
  anode_kernel<<<dim3(NWG), dim3(NTHREADS), 0, stream>>>(
      ts, y0, W1, b1, W2, b2, W3, b3, (float*)d_out);
}